// Round 17
// baseline (668.648 us; speedup 1.0000x reference)
//
#include <hip/hip_runtime.h>
#include <hip/hip_bf16.h>

// GAT: 3 layers. N=50000 nodes, E=800000 edges, H=4 heads.
// R17: fp16 gather arrays. R18: f16-native GEMMs. R20: 1-wave half4
// gathers -> 615us. R21: W2 single-f16 for final GEMM (head-mean x0.25
// scales quant error) -> 592.7us. absmax pinned at 2^-11 since R0.
// R22: GEMMs were barrier-bound (MfmaUtil 11.6%, 2 barriers+vmcnt(0)
// per K-chunk just to reshape A row-major -> fragment order via LDS).
// All A-operands are produced by OUR kernels -> producers now write A
// directly in MFMA fragment order Ap[tile][c][lane][8] (tile=n>>4,
// c=k>>5, lane=(n&15)+16*((k>>3)&3), j=k&7). GEMM inner loop = pure
// coalesced register loads + MFMAs: NO LDS, NO barriers. h1 stays
// row-major (gather/elr2 consumers); h0/Af16/feat-splits single-use.
// Pad tiles (to 3128) read junk -> feeds only discarded rows. NO
// arithmetic change: absmax must stay exactly 4.882812e-4.
// R23/R24: resubmits (container infra failures, no counters). Audit
// found zero fault mechanisms; buffer extents verified exact. If this
// fails again: next round submits known-good R21 as discriminator.

#define NN 50000
#define NE 800000
#define NH_HEADS 4

typedef __attribute__((ext_vector_type(8))) short short8;
typedef __attribute__((ext_vector_type(8))) _Float16 half8;
typedef __attribute__((ext_vector_type(4))) _Float16 half4;
typedef __attribute__((ext_vector_type(4))) float floatx4;

__device__ inline float bf2f(short s) {
    union { unsigned u; float f; } v; v.u = ((unsigned)(unsigned short)s) << 16;
    return v.f;
}
__device__ inline short f2bf_rne(float x) {
    union { float f; unsigned u; } v; v.f = x;
    unsigned r = v.u + 0x7fff + ((v.u >> 16) & 1);
    return (short)(r >> 16);
}
// truncation hi/lo split: hi = trunc16(x), lo = trunc16(x - hi)
__device__ inline void split1(float x, short& h, short& l) {
    union { float f; unsigned u; } v; v.f = x;
    h = (short)(v.u >> 16);
    union { float f; unsigned u; } rv; rv.f = v.f - bf2f(h);
    l = (short)(rv.u >> 16);
}

// ---------------- CSR build ----------------

__global__ void hist_kernel(const int* __restrict__ dst, int* __restrict__ deg, int E) {
    int e = blockIdx.x * 256 + threadIdx.x;
    if (e < E) atomicAdd(&deg[dst[e]], 1);
}

__global__ void scan_block_kernel(const int* __restrict__ deg, int* __restrict__ offs,
                                  int* __restrict__ bsums, int n) {
    __shared__ int s[256];
    int tid = threadIdx.x;
    int i = blockIdx.x * 256 + tid;
    int v = (i < n) ? deg[i] : 0;
    s[tid] = v;
    __syncthreads();
    for (int off = 1; off < 256; off <<= 1) {
        int x = (tid >= off) ? s[tid - off] : 0;
        __syncthreads();
        s[tid] += x;
        __syncthreads();
    }
    if (i < n) offs[i] = s[tid] - v;
    if (tid == 255) bsums[blockIdx.x] = s[255];
}

__global__ void scan_sums_kernel(const int* __restrict__ bsums, int* __restrict__ boffs, int nb) {
    __shared__ int s[256];
    int tid = threadIdx.x;
    int v = (tid < nb) ? bsums[tid] : 0;
    s[tid] = v;
    __syncthreads();
    for (int off = 1; off < 256; off <<= 1) {
        int x = (tid >= off) ? s[tid - off] : 0;
        __syncthreads();
        s[tid] += x;
        __syncthreads();
    }
    boffs[tid] = s[tid] - v;
}

__global__ void add_offs_kernel(int* __restrict__ offs, const int* __restrict__ boffs,
                                int* __restrict__ cursor, int n, int total) {
    int i = blockIdx.x * 256 + threadIdx.x;
    if (i < n) {
        int o = offs[i] + boffs[blockIdx.x];
        offs[i] = o;
        cursor[i] = o;
    }
    if (i == 0) offs[n] = total;
}

__global__ void scatter_kernel(const int* __restrict__ src, const int* __restrict__ dst,
                               int* __restrict__ cursor, int* __restrict__ psrc, int E) {
    int e = blockIdx.x * 256 + threadIdx.x;
    if (e < E) {
        int p = atomicAdd(&cursor[dst[e]], 1);
        psrc[p] = src[e];
    }
}

// ---------------- feat (row-major fp32) -> PERMUTED bf16 hi/lo ----------------
// thread = (n, octet o in [0,16)): k = o*8..o*8+7. tile=n>>4, c=o>>2,
// lane=(n&15)+16*(o&3). dest short8 idx = (tile*4 + c)*64 + lane.

__global__ __launch_bounds__(256) void splitA_perm(const float* __restrict__ A,
                                                   short* __restrict__ hi,
                                                   short* __restrict__ lo,
                                                   int total) {
    int tid = blockIdx.x * 256 + threadIdx.x;
    if (tid >= total) return;
    int n = tid >> 4, o = tid & 15;
    const float* p = A + (size_t)n * 128 + o * 8;
    float4 x0 = ((const float4*)p)[0];
    float4 x1 = ((const float4*)p)[1];
    float xs[8] = {x0.x, x0.y, x0.z, x0.w, x1.x, x1.y, x1.z, x1.w};
    short8 hv, lv;
#pragma unroll
    for (int j = 0; j < 8; ++j) { short h, l; split1(xs[j], h, l); hv[j] = h; lv[j] = l; }
    size_t idx = ((size_t)(n >> 4) * 4 + (o >> 2)) * 64 + (n & 15) + 16 * (o & 3);
    ((short8*)hi)[idx] = hv;
    ((short8*)lo)[idx] = lv;
}

// ---------------- B -> hi/lo in MFMA B-fragment order ----------------
// offset (x8) = (c*(N/16)+g)*64 + lane ; lane=(n&15)+16*((k&31)>>3), j=k&7

__global__ __launch_bounds__(256) void splitB_kernel(const float* __restrict__ B,
                                                     short* __restrict__ hi,
                                                     short* __restrict__ lo,
                                                     int K, int N) {
    int tid = blockIdx.x * 256 + threadIdx.x;
    int NG = N >> 4;
    int total = (K >> 5) * NG * 64;
    if (tid >= total) return;
    int lane = tid & 63;
    int rc = tid >> 6;
    int g = rc % NG, c = rc / NG;
    int n = g * 16 + (lane & 15);
    int k = c * 32 + (lane >> 4) * 8;
    short8 hv, lv;
#pragma unroll
    for (int j = 0; j < 8; ++j) {
        float x = B[(size_t)(k + j) * N + n];
        short h = f2bf_rne(x);
        hv[j] = h;
        lv[j] = f2bf_rne(x - bf2f(h));
    }
    ((short8*)hi)[tid] = hv;
    ((short8*)lo)[tid] = lv;
}

// f16 hi/lo variant (for W1)
__global__ __launch_bounds__(256) void splitB_f16_kernel(const float* __restrict__ B,
                                                         _Float16* __restrict__ hi,
                                                         _Float16* __restrict__ lo,
                                                         int K, int N) {
    int tid = blockIdx.x * 256 + threadIdx.x;
    int NG = N >> 4;
    int total = (K >> 5) * NG * 64;
    if (tid >= total) return;
    int lane = tid & 63;
    int rc = tid >> 6;
    int g = rc % NG, c = rc / NG;
    int n = g * 16 + (lane & 15);
    int k = c * 32 + (lane >> 4) * 8;
    half8 hv, lv;
#pragma unroll
    for (int j = 0; j < 8; ++j) {
        float x = B[(size_t)(k + j) * N + n];
        _Float16 h = (_Float16)x;
        hv[j] = h;
        lv[j] = (_Float16)(x - (float)h);
    }
    ((half8*)hi)[tid] = hv;
    ((half8*)lo)[tid] = lv;
}

// permuted-W2 f16 HI ONLY: Bp[h*256+k, c] = W2[k, h*256+c]; K=1024, N=256
__global__ __launch_bounds__(256) void splitB2_f16s_kernel(const float* __restrict__ W2,
                                                           _Float16* __restrict__ hi) {
    int tid = blockIdx.x * 256 + threadIdx.x;
    const int NG = 16;
    int total = (1024 >> 5) * NG * 64;   // 32768
    if (tid >= total) return;
    int lane = tid & 63;
    int rc = tid >> 6;
    int g = rc % NG, c = rc / NG;
    int n = g * 16 + (lane & 15);
    int kk = c * 32 + (lane >> 4) * 8;
    half8 hv;
#pragma unroll
    for (int j = 0; j < 8; ++j) {
        int kg = kk + j;
        int h = kg >> 8, k = kg & 255;
        hv[j] = (_Float16)W2[(size_t)k * 1024 + h * 256 + n];
    }
    ((half8*)hi)[tid] = hv;
}

// ---------------- MFMA GEMMs, N=256: barrier-free, fragment-order A ----------------
// block: 64 rows x 256 cols; wave w owns cols [w*64,(w+1)*64); tiles tile0..+3.
// A/B both fragment-order -> pure coalesced register loads, no LDS/barriers.
// Fused elr epilogue (alv!=null): from fp32 acc, pre-quantization.

__device__ inline floatx4 mfma16(short8 a, short8 b, floatx4 c) {
    return __builtin_amdgcn_mfma_f32_16x16x32_bf16(a, b, c, 0, 0, 0);
}
__device__ inline floatx4 mfma16h(half8 a, half8 b, floatx4 c) {
    return __builtin_amdgcn_mfma_f32_16x16x32_f16(a, b, c, 0, 0, 0);
}

// bf16-pair A x bf16-pair B (3-MFMA). Layer 0 (A = permuted feat split).
__global__ __launch_bounds__(256) void gemm_n256l(const short* __restrict__ Ahi,
                                                  const short* __restrict__ Alo,
                                                  const short* __restrict__ Bh,
                                                  const short* __restrict__ Bl,
                                                  _Float16* __restrict__ Cf,
                                                  const float* __restrict__ alv,
                                                  const float* __restrict__ arv,
                                                  float* __restrict__ elo,
                                                  float* __restrict__ ero,
                                                  int M, int K) {
    int KC = K >> 5;
    int t = threadIdx.x;
    int lane = t & 63;
    int w = t >> 6;
    int bm = blockIdx.x * 64;
    int tile0 = blockIdx.x * 4;
    int g0 = w * 4;
    const short8* pAh = (const short8*)Ahi;
    const short8* pAl = (const short8*)Alo;
    const short8* pBh = (const short8*)Bh;
    const short8* pBl = (const short8*)Bl;

    floatx4 acc[4][4] = {};

    for (int c = 0; c < KC; ++c) {
        short8 ah[4], al4[4], bh[4], bl[4];
#pragma unroll
        for (int mt = 0; mt < 4; ++mt) {
            size_t ia = ((size_t)(tile0 + mt) * KC + c) * 64 + lane;
            ah[mt] = pAh[ia];
            al4[mt] = pAl[ia];
        }
#pragma unroll
        for (int g = 0; g < 4; ++g) {
            size_t ib = ((size_t)c * 16 + g0 + g) * 64 + lane;
            bh[g] = pBh[ib];
            bl[g] = pBl[ib];
        }
#pragma unroll
        for (int mt = 0; mt < 4; ++mt) {
#pragma unroll
            for (int g = 0; g < 4; ++g) {
                acc[mt][g] = mfma16(ah[mt], bh[g], acc[mt][g]);
                acc[mt][g] = mfma16(al4[mt], bh[g], acc[mt][g]);
                acc[mt][g] = mfma16(ah[mt], bl[g], acc[mt][g]);
            }
        }
    }

    // C/D layout: col = lane&15, row = (lane>>4)*4 + reg
    int rowb = bm + (lane >> 4) * 4;
    int colb = w * 64 + (lane & 15);
#pragma unroll
    for (int mt = 0; mt < 4; ++mt) {
#pragma unroll
        for (int r = 0; r < 4; ++r) {
            int rr = rowb + mt * 16 + r;
            if (rr < M) {
#pragma unroll
                for (int g = 0; g < 4; ++g) {
                    Cf[(size_t)rr * 256 + colb + g * 16] = (_Float16)acc[mt][g][r];
                }
            }
        }
    }

    // fused elr: el[rr,w] = sum_f z[rr, w*64+f]*alv[w*64+f] (f = (lane&15)+g*16)
    if (alv) {
        float alr[4], arr_[4];
#pragma unroll
        for (int g = 0; g < 4; ++g) {
            int f = w * 64 + (lane & 15) + g * 16;
            alr[g] = alv[f];
            arr_[g] = arv[f];
        }
#pragma unroll
        for (int mt = 0; mt < 4; ++mt) {
#pragma unroll
            for (int r = 0; r < 4; ++r) {
                float se = acc[mt][0][r] * alr[0] + acc[mt][1][r] * alr[1] +
                           acc[mt][2][r] * alr[2] + acc[mt][3][r] * alr[3];
                float sr = acc[mt][0][r] * arr_[0] + acc[mt][1][r] * arr_[1] +
                           acc[mt][2][r] * arr_[2] + acc[mt][3][r] * arr_[3];
                se += __shfl_xor(se, 1); se += __shfl_xor(se, 2);
                se += __shfl_xor(se, 4); se += __shfl_xor(se, 8);
                sr += __shfl_xor(sr, 1); sr += __shfl_xor(sr, 2);
                sr += __shfl_xor(sr, 4); sr += __shfl_xor(sr, 8);
                int rr = rowb + mt * 16 + r;
                if ((lane & 15) == 0 && rr < M) {
                    elo[rr * 4 + w] = se;
                    ero[rr * 4 + w] = sr;
                }
            }
        }
    }
}

// single-f16 A (fragment-order) x f16 B (pair if Bl!=null, else single).
__global__ __launch_bounds__(256) void gemm_f16_n256(const _Float16* __restrict__ A,
                                                     const _Float16* __restrict__ Bh,
                                                     const _Float16* __restrict__ Bl,
                                                     const float* __restrict__ bias4,
                                                     float* __restrict__ C,
                                                     _Float16* __restrict__ Cf,
                                                     const float* __restrict__ alv,
                                                     const float* __restrict__ arv,
                                                     float* __restrict__ elo,
                                                     float* __restrict__ ero,
                                                     int M, int K) {
    int KC = K >> 5;
    int t = threadIdx.x;
    int lane = t & 63;
    int w = t >> 6;
    int bm = blockIdx.x * 64;
    int tile0 = blockIdx.x * 4;
    int g0 = w * 4;
    const half8* pA = (const half8*)A;
    const half8* pBh = (const half8*)Bh;
    const half8* pBl = (const half8*)Bl;
    bool dual = (Bl != nullptr);

    floatx4 acc[4][4] = {};

    for (int c = 0; c < KC; ++c) {
        half8 a[4], bh[4], bl[4];
#pragma unroll
        for (int mt = 0; mt < 4; ++mt) {
            a[mt] = pA[((size_t)(tile0 + mt) * KC + c) * 64 + lane];
        }
#pragma unroll
        for (int g = 0; g < 4; ++g) {
            bh[g] = pBh[((size_t)c * 16 + g0 + g) * 64 + lane];
        }
        if (dual) {
#pragma unroll
            for (int g = 0; g < 4; ++g) {
                bl[g] = pBl[((size_t)c * 16 + g0 + g) * 64 + lane];
            }
        }
#pragma unroll
        for (int mt = 0; mt < 4; ++mt) {
#pragma unroll
            for (int g = 0; g < 4; ++g) {
                acc[mt][g] = mfma16h(a[mt], bh[g], acc[mt][g]);
            }
            if (dual) {
#pragma unroll
                for (int g = 0; g < 4; ++g) {
                    acc[mt][g] = mfma16h(a[mt], bl[g], acc[mt][g]);
                }
            }
        }
    }

    // C/D layout: col = lane&15, row = (lane>>4)*4 + reg
    int rowb = bm + (lane >> 4) * 4;
    int colb = w * 64 + (lane & 15);
#pragma unroll
    for (int mt = 0; mt < 4; ++mt) {
#pragma unroll
        for (int r = 0; r < 4; ++r) {
            int rr = rowb + mt * 16 + r;
            if (rr < M) {
#pragma unroll
                for (int g = 0; g < 4; ++g) {
                    int col = colb + g * 16;
                    float v = acc[mt][g][r];
                    if (bias4) {
                        v = 0.25f * (v + bias4[col] + bias4[col + 256] +
                                     bias4[col + 512] + bias4[col + 768]);
                    }
                    if (Cf) Cf[(size_t)rr * 256 + col] = (_Float16)v;
                    else    C[(size_t)rr * 256 + col] = v;
                }
            }
        }
    }

    // fused elr from fp32 acc
    if (alv) {
        float alr[4], arr_[4];
#pragma unroll
        for (int g = 0; g < 4; ++g) {
            int f = w * 64 + (lane & 15) + g * 16;
            alr[g] = alv[f];
            arr_[g] = arv[f];
        }
#pragma unroll
        for (int mt = 0; mt < 4; ++mt) {
#pragma unroll
            for (int r = 0; r < 4; ++r) {
                float se = acc[mt][0][r] * alr[0] + acc[mt][1][r] * alr[1] +
                           acc[mt][2][r] * alr[2] + acc[mt][3][r] * alr[3];
                float sr = acc[mt][0][r] * arr_[0] + acc[mt][1][r] * arr_[1] +
                           acc[mt][2][r] * arr_[2] + acc[mt][3][r] * arr_[3];
                se += __shfl_xor(se, 1); se += __shfl_xor(se, 2);
                se += __shfl_xor(se, 4); se += __shfl_xor(se, 8);
                sr += __shfl_xor(sr, 1); sr += __shfl_xor(sr, 2);
                sr += __shfl_xor(sr, 4); sr += __shfl_xor(sr, 8);
                int rr = rowb + mt * 16 + r;
                if ((lane & 15) == 0 && rr < M) {
                    elo[rr * 4 + w] = se;
                    ero[rr * 4 + w] = sr;
                }
            }
        }
    }
}

// ---------------- attention score parts (layer 2) ----------------

// val[h*256+k] = sum_j W2[k,h*256+j]*al2[h,j] ; var likewise with ar2
__global__ __launch_bounds__(256) void proj_av_kernel(const float* __restrict__ W2,
                                                      const float* __restrict__ al2,
                                                      const float* __restrict__ ar2,
                                                      float* __restrict__ val,
                                                      float* __restrict__ var_) {
    int gid = blockIdx.x * 256 + threadIdx.x;
    int w = gid >> 6;
    int lane = threadIdx.x & 63;
    if (w >= 1024) return;
    int h = w >> 8, k = w & 255;
    const float* wrow = W2 + (size_t)k * 1024 + h * 256;
    const float* ap = al2 + h * 256;
    const float* rp = ar2 + h * 256;
    float sv = 0.f, sr = 0.f;
    for (int j = lane; j < 256; j += 64) {
        float x = wrow[j];
        sv += x * ap[j];
        sr += x * rp[j];
    }
#pragma unroll
    for (int off = 32; off > 0; off >>= 1) {
        sv += __shfl_down(sv, off);
        sr += __shfl_down(sr, off);
    }
    if (lane == 0) { val[w] = sv; var_[w] = sr; }
}

// el[n,h] = h1[n,:]·val[h,:], er likewise (h1 fp16 row-major)
__global__ __launch_bounds__(256) void elr2_kernel(const _Float16* __restrict__ h1,
                                                   const float* __restrict__ val,
                                                   const float* __restrict__ var_,
                                                   float* __restrict__ el,
                                                   float* __restrict__ er) {
    int gid = blockIdx.x * 256 + threadIdx.x;
    int w = gid >> 6;
    int lane = threadIdx.x & 63;
    if (w >= NN * 4) return;
    int n = w >> 2, h = w & 3;
    const _Float16* hr = h1 + (size_t)n * 256;
    const float* vp = val + h * 256;
    const float* rp = var_ + h * 256;
    float se = 0.f, sr = 0.f;
    for (int k = lane; k < 256; k += 64) {
        float x = (float)hr[k];
        se += x * vp[k];
        sr += x * rp[k];
    }
#pragma unroll
    for (int off = 32; off > 0; off >>= 1) {
        se += __shfl_down(se, off);
        sr += __shfl_down(sr, off);
    }
    if (lane == 0) { el[w] = se; er[w] = sr; }
}

// ---------------- aggregation: 1-wave blocks, half4 loads ----------------
// Block = 64 lanes = one node. Lane l owns cols 4l..4l+3 (head h = l>>4).
// p-phase: chunk = 16 edges x 4 heads = 64 lanes; den via shfl_xor.

// z-gather (layers 0 & 1): elu epilogue, f16 out. perm=0: row-major [N,256]
// (h1). perm=1: fragment-order KC=8 (h0, consumed only by L1 GEMM).
__global__ __launch_bounds__(64) void agg_z64_kernel(const _Float16* __restrict__ z,
                                                     const float* __restrict__ el,
                                                     const float* __restrict__ er,
                                                     const int* __restrict__ offs,
                                                     const int* __restrict__ psrc,
                                                     const float* __restrict__ bias,
                                                     _Float16* __restrict__ out,
                                                     int perm) {
    int n = blockIdx.x;
    int l = threadIdx.x;
    __shared__ float p_lds[16][4];
    __shared__ int src_lds[16];
    __shared__ float den_lds[4];
    if (l < 4) den_lds[l] = 0.f;
    int e_local = l >> 2, hh = l & 3;
    int h = l >> 4;
    float er_n = er[n * 4 + hh];
    int beg = offs[n], end = offs[n + 1];
    float a0 = 0.f, a1 = 0.f, a2 = 0.f, a3 = 0.f;
    for (int base = beg; base < end; base += 16) {
        int cnt = min(16, end - base);
        __syncthreads();
        float p = 0.f;
        if (e_local < cnt) {
            int s = psrc[base + e_local];
            if (hh == 0) src_lds[e_local] = s;
            float sc = el[s * 4 + hh] + er_n;
            sc = (sc > 0.f) ? sc : 0.2f * sc;
            p = __expf(sc);
            p_lds[e_local][hh] = p;
        }
        float d = p;
        d += __shfl_xor(d, 4);  d += __shfl_xor(d, 8);
        d += __shfl_xor(d, 16); d += __shfl_xor(d, 32);
        if (l < 4) den_lds[l] += d;
        __syncthreads();
        for (int e = 0; e < cnt; ++e) {
            half4 v = *(const half4*)(z + (size_t)src_lds[e] * 256 + (l << 2));
            float pe = p_lds[e][h];
            a0 += pe * (float)v[0];
            a1 += pe * (float)v[1];
            a2 += pe * (float)v[2];
            a3 += pe * (float)v[3];
        }
    }
    __syncthreads();
    float rd = 1.f / fmaxf(den_lds[h], 1e-9f);
    float vals[4] = {a0, a1, a2, a3};
    half4 o;
#pragma unroll
    for (int j = 0; j < 4; ++j) {
        float x = vals[j] * rd + bias[(l << 2) + j];
        x = (x > 0.f) ? x : (__expf(x) - 1.f);
        o[j] = (_Float16)x;
    }
    if (perm) {
        // k = 4l..4l+3: tile=n>>4, c=l>>3, lane_in=(n&15)+16*((l>>1)&3), j0=(l&1)*4
        size_t off = ((((size_t)(n >> 4) * 8 + (l >> 3)) * 64 +
                       (n & 15) + 16 * ((l >> 1) & 3)) << 3) + ((l & 1) << 2);
        *(half4*)(out + off) = o;
    } else {
        *(half4*)(out + (size_t)n * 256 + (l << 2)) = o;
    }
}

// layer-2 aggregation of h1 (fp16) -> fragment-order f16 A (KC=32, final GEMM).
__global__ __launch_bounds__(64) void aggH_64_kernel(const _Float16* __restrict__ h1,
                                                     const float* __restrict__ el,
                                                     const float* __restrict__ er,
                                                     const int* __restrict__ offs,
                                                     const int* __restrict__ psrc,
                                                     _Float16* __restrict__ oA) {
    int n = blockIdx.x;
    int l = threadIdx.x;
    __shared__ __align__(16) float p_lds[16][4];
    __shared__ int src_lds[16];
    __shared__ float den_lds[4];
    if (l < 4) den_lds[l] = 0.f;
    int e_local = l >> 2, hh = l & 3;
    float er_n = er[n * 4 + hh];
    int beg = offs[n], end = offs[n + 1];
    float acc[4][4] = {};   // [head][colj]
    for (int base = beg; base < end; base += 16) {
        int cnt = min(16, end - base);
        __syncthreads();
        float p = 0.f;
        if (e_local < cnt) {
            int s = psrc[base + e_local];
            if (hh == 0) src_lds[e_local] = s;
            float sc = el[s * 4 + hh] + er_n;
            sc = (sc > 0.f) ? sc : 0.2f * sc;
            p = __expf(sc);
            p_lds[e_local][hh] = p;
        }
        float d = p;
        d += __shfl_xor(d, 4);  d += __shfl_xor(d, 8);
        d += __shfl_xor(d, 16); d += __shfl_xor(d, 32);
        if (l < 4) den_lds[l] += d;
        __syncthreads();
        for (int e = 0; e < cnt; ++e) {
            half4 v = *(const half4*)(h1 + (size_t)src_lds[e] * 256 + (l << 2));
            float vf0 = (float)v[0], vf1 = (float)v[1];
            float vf2 = (float)v[2], vf3 = (float)v[3];
            floatx4 pv = *(const floatx4*)&p_lds[e][0];
#pragma unroll
            for (int hd = 0; hd < 4; ++hd) {
                acc[hd][0] += pv[hd] * vf0;
                acc[hd][1] += pv[hd] * vf1;
                acc[hd][2] += pv[hd] * vf2;
                acc[hd][3] += pv[hd] * vf3;
            }
        }
    }
    __syncthreads();
    // k = hd*256 + 4l + j: tile=n>>4, c=hd*8+(l>>3), lane_in=(n&15)+16*((l>>1)&3)
    size_t tb = (size_t)(n >> 4) * 32;
    int lane_in = (n & 15) + 16 * ((l >> 1) & 3);
    int j0 = (l & 1) << 2;
#pragma unroll
    for (int hd = 0; hd < 4; ++hd) {
        float rd = 1.f / fmaxf(den_lds[hd], 1e-9f);
        half4 o;
#pragma unroll
        for (int j = 0; j < 4; ++j) o[j] = (_Float16)(acc[hd][j] * rd);
        size_t off = (((tb + hd * 8 + (l >> 3)) * 64 + lane_in) << 3) + j0;
        *(half4*)(oA + off) = o;
    }
}

// ---------------- launch ----------------

extern "C" void kernel_launch(void* const* d_in, const int* in_sizes, int n_in,
                              void* d_out, int out_size, void* d_ws, size_t ws_size,
                              hipStream_t stream) {
    const float* feat = (const float*)d_in[0];
    const float* W0 = (const float*)d_in[1];
    const float* al0 = (const float*)d_in[2];
    const float* ar0 = (const float*)d_in[3];
    const float* b0 = (const float*)d_in[4];
    const float* W1 = (const float*)d_in[5];
    const float* al1 = (const float*)d_in[6];
    const float* ar1 = (const float*)d_in[7];
    const float* b1 = (const float*)d_in[8];
    const float* W2 = (const float*)d_in[9];
    const float* al2 = (const float*)d_in[10];
    const float* ar2 = (const float*)d_in[11];
    const float* b2 = (const float*)d_in[12];
    const int* src = (const int*)d_in[13];
    const int* dst = (const int*)d_in[14];
    float* out = (float*)d_out;

    int mb64 = (NN + 63) / 64;           // 782 blocks
    size_t TIL = (size_t)mb64 * 4;       // 3128 padded tiles

    // ---- workspace layout (~262.5 MB), time-multiplexed big slots ----
    float* slotA = (float*)d_ws;
    _Float16* zh = (_Float16*)slotA;                      // [N,256] fp16 (z slot)
    short* feathi = (short*)(slotA + (size_t)NN * 256);   // TIL*4*512 shorts (perm)
    short* featlo = feathi + TIL * 4 * 512;
    _Float16* Af16 = (_Float16*)slotA;                    // TIL*32*512 halves (perm)
    float* slotB = slotA + (size_t)NN * 1024;
    _Float16* h0f = (_Float16*)slotB;                     // TIL*8*512 halves (perm)
    _Float16* h1h = (_Float16*)slotB;                     // [N,256] f16 row-major
    float* el = slotB + (size_t)NN * 256;                 // 200000
    float* er = el + (size_t)NN * NH_HEADS;               // 200000
    int* deg = (int*)(er + (size_t)NN * NH_HEADS);        // 50000
    int* offs = deg + NN;                                 // 50001 (+1 pad)
    int* cursor = offs + NN + 2;                          // 50000
    int* bsums = cursor + NN;                             // 256
    int* boffs = bsums + 256;                             // 256
    int* psrc = boffs + 256;                              // 800000 (+2 pad)
    short* Bh = (short*)(psrc + NE + 2);                  // 262144 shorts / half8s
    short* Bl = Bh + 262144;                              // 262144 shorts
    float* val = (float*)(Bl + 262144);                   // 1024
    float* var_ = val + 1024;                             // 1024

    // ---- CSR build (by dst) ----
    hipMemsetAsync(deg, 0, NN * sizeof(int), stream);
    hist_kernel<<<(NE + 255) / 256, 256, 0, stream>>>(dst, deg, NE);
    int nb = (NN + 255) / 256;
    scan_block_kernel<<<nb, 256, 0, stream>>>(deg, offs, bsums, NN);
    scan_sums_kernel<<<1, 256, 0, stream>>>(bsums, boffs, nb);
    add_offs_kernel<<<nb, 256, 0, stream>>>(offs, boffs, cursor, NN, NE);
    scatter_kernel<<<(NE + 255) / 256, 256, 0, stream>>>(src, dst, cursor, psrc, NE);

    // ---- layer 0: 128 -> 4x64, elu (barrier-free bf16-pair GEMM; z fp16) ----
    splitA_perm<<<(NN * 16 + 255) / 256, 256, 0, stream>>>(feat, feathi, featlo, NN * 16);
    splitB_kernel<<<(4096 + 255) / 256, 256, 0, stream>>>(W0, Bh, Bl, 128, 256);
    gemm_n256l<<<mb64, 256, 0, stream>>>(feathi, featlo, Bh, Bl, zh,
                                         al0, ar0, el, er, NN, 128);
    agg_z64_kernel<<<NN, 64, 0, stream>>>(zh, el, er, offs, psrc, b0, h0f, 1);

    // ---- layer 1: 256 -> 4x64, elu (barrier-free f16 GEMM, B pair) ----
    splitB_f16_kernel<<<(8192 + 255) / 256, 256, 0, stream>>>(W1, (_Float16*)Bh,
                                                              (_Float16*)Bl, 256, 256);
    gemm_f16_n256<<<mb64, 256, 0, stream>>>(h0f, (const _Float16*)Bh, (const _Float16*)Bl,
                                            nullptr, nullptr, zh, al1, ar1, el, er,
                                            NN, 256);
    agg_z64_kernel<<<NN, 64, 0, stream>>>(zh, el, er, offs, psrc, b1, h1h, 0);

    // ---- layer 2: score from aggregated h1, then f16 K=1024 projection ----
    proj_av_kernel<<<256, 256, 0, stream>>>(W2, al2, ar2, val, var_);
    elr2_kernel<<<NN, 256, 0, stream>>>(h1h, val, var_, el, er);
    aggH_64_kernel<<<NN, 64, 0, stream>>>(h1h, el, er, offs, psrc, Af16);
    splitB2_f16s_kernel<<<(32768 + 255) / 256, 256, 0, stream>>>(W2, (_Float16*)Bh);
    gemm_f16_n256<<<mb64, 256, 0, stream>>>(Af16, (const _Float16*)Bh, nullptr,
                                            b2, out, nullptr, nullptr, nullptr,
                                            nullptr, nullptr, NN, 1024);
}

// Round 18
// 618.512 us; speedup vs baseline: 1.0811x; 1.0811x over previous
//
#include <hip/hip_runtime.h>
#include <hip/hip_bf16.h>

// GAT: 3 layers. N=50000 nodes, E=800000 edges, H=4 heads.
// R20: 1-wave half4 gathers -> 615us. R21: W2 single-f16 final GEMM ->
// 592.7us. R22 (NET HURT, 668us): producer-side fragment-order writes
// doubled aggH WRITE_SIZE (100->200MB, scattered 8B stores) though the
// barrier-free GEMM itself was sound (absmax unchanged).
// R25: barrier-free GEMM KEPT, producer permutation DROPPED. MFMA lane
// l's A-fragment is A[row=tile*16+(l&15)][c*32+(l>>4)*8 ..+8] -- a 16B
// load at a per-lane address into ROW-MAJOR A (wave touches 16 full
// 64B lines, 100% utilized, L2-local). Producers revert to contiguous
// writes (R21): aggH/agg_z64/splitA all row-major. No LDS, no barriers
// in GEMMs. absmax must stay exactly 4.882812e-4.

#define NN 50000
#define NE 800000
#define NH_HEADS 4

typedef __attribute__((ext_vector_type(8))) short short8;
typedef __attribute__((ext_vector_type(8))) _Float16 half8;
typedef __attribute__((ext_vector_type(4))) _Float16 half4;
typedef __attribute__((ext_vector_type(4))) float floatx4;

__device__ inline float bf2f(short s) {
    union { unsigned u; float f; } v; v.u = ((unsigned)(unsigned short)s) << 16;
    return v.f;
}
__device__ inline short f2bf_rne(float x) {
    union { float f; unsigned u; } v; v.f = x;
    unsigned r = v.u + 0x7fff + ((v.u >> 16) & 1);
    return (short)(r >> 16);
}
// truncation hi/lo split: hi = trunc16(x), lo = trunc16(x - hi)
__device__ inline void split1(float x, short& h, short& l) {
    union { float f; unsigned u; } v; v.f = x;
    h = (short)(v.u >> 16);
    union { float f; unsigned u; } rv; rv.f = v.f - bf2f(h);
    l = (short)(rv.u >> 16);
}

// ---------------- CSR build ----------------

__global__ void hist_kernel(const int* __restrict__ dst, int* __restrict__ deg, int E) {
    int e = blockIdx.x * 256 + threadIdx.x;
    if (e < E) atomicAdd(&deg[dst[e]], 1);
}

__global__ void scan_block_kernel(const int* __restrict__ deg, int* __restrict__ offs,
                                  int* __restrict__ bsums, int n) {
    __shared__ int s[256];
    int tid = threadIdx.x;
    int i = blockIdx.x * 256 + tid;
    int v = (i < n) ? deg[i] : 0;
    s[tid] = v;
    __syncthreads();
    for (int off = 1; off < 256; off <<= 1) {
        int x = (tid >= off) ? s[tid - off] : 0;
        __syncthreads();
        s[tid] += x;
        __syncthreads();
    }
    if (i < n) offs[i] = s[tid] - v;
    if (tid == 255) bsums[blockIdx.x] = s[255];
}

__global__ void scan_sums_kernel(const int* __restrict__ bsums, int* __restrict__ boffs, int nb) {
    __shared__ int s[256];
    int tid = threadIdx.x;
    int v = (tid < nb) ? bsums[tid] : 0;
    s[tid] = v;
    __syncthreads();
    for (int off = 1; off < 256; off <<= 1) {
        int x = (tid >= off) ? s[tid - off] : 0;
        __syncthreads();
        s[tid] += x;
        __syncthreads();
    }
    boffs[tid] = s[tid] - v;
}

__global__ void add_offs_kernel(int* __restrict__ offs, const int* __restrict__ boffs,
                                int* __restrict__ cursor, int n, int total) {
    int i = blockIdx.x * 256 + threadIdx.x;
    if (i < n) {
        int o = offs[i] + boffs[blockIdx.x];
        offs[i] = o;
        cursor[i] = o;
    }
    if (i == 0) offs[n] = total;
}

__global__ void scatter_kernel(const int* __restrict__ src, const int* __restrict__ dst,
                               int* __restrict__ cursor, int* __restrict__ psrc, int E) {
    int e = blockIdx.x * 256 + threadIdx.x;
    if (e < E) {
        int p = atomicAdd(&cursor[dst[e]], 1);
        psrc[p] = src[e];
    }
}

// ---------------- A (row-major fp32) -> row-major bf16 hi/lo ----------------

__global__ __launch_bounds__(256) void splitA_rm(const float* __restrict__ A,
                                                 short* __restrict__ hi,
                                                 short* __restrict__ lo,
                                                 int total8) {
    int tid = blockIdx.x * 256 + threadIdx.x;
    if (tid >= total8) return;
    const float* p = A + (size_t)tid * 8;
    float4 x0 = ((const float4*)p)[0];
    float4 x1 = ((const float4*)p)[1];
    float xs[8] = {x0.x, x0.y, x0.z, x0.w, x1.x, x1.y, x1.z, x1.w};
    short8 hv, lv;
#pragma unroll
    for (int j = 0; j < 8; ++j) { short h, l; split1(xs[j], h, l); hv[j] = h; lv[j] = l; }
    ((short8*)hi)[tid] = hv;
    ((short8*)lo)[tid] = lv;
}

// ---------------- B -> hi/lo in MFMA B-fragment order ----------------
// offset (x8) = (c*(N/16)+g)*64 + lane ; lane=(n&15)+16*((k&31)>>3), j=k&7

__global__ __launch_bounds__(256) void splitB_kernel(const float* __restrict__ B,
                                                     short* __restrict__ hi,
                                                     short* __restrict__ lo,
                                                     int K, int N) {
    int tid = blockIdx.x * 256 + threadIdx.x;
    int NG = N >> 4;
    int total = (K >> 5) * NG * 64;
    if (tid >= total) return;
    int lane = tid & 63;
    int rc = tid >> 6;
    int g = rc % NG, c = rc / NG;
    int n = g * 16 + (lane & 15);
    int k = c * 32 + (lane >> 4) * 8;
    short8 hv, lv;
#pragma unroll
    for (int j = 0; j < 8; ++j) {
        float x = B[(size_t)(k + j) * N + n];
        short h = f2bf_rne(x);
        hv[j] = h;
        lv[j] = f2bf_rne(x - bf2f(h));
    }
    ((short8*)hi)[tid] = hv;
    ((short8*)lo)[tid] = lv;
}

// f16 hi/lo variant (for W1)
__global__ __launch_bounds__(256) void splitB_f16_kernel(const float* __restrict__ B,
                                                         _Float16* __restrict__ hi,
                                                         _Float16* __restrict__ lo,
                                                         int K, int N) {
    int tid = blockIdx.x * 256 + threadIdx.x;
    int NG = N >> 4;
    int total = (K >> 5) * NG * 64;
    if (tid >= total) return;
    int lane = tid & 63;
    int rc = tid >> 6;
    int g = rc % NG, c = rc / NG;
    int n = g * 16 + (lane & 15);
    int k = c * 32 + (lane >> 4) * 8;
    half8 hv, lv;
#pragma unroll
    for (int j = 0; j < 8; ++j) {
        float x = B[(size_t)(k + j) * N + n];
        _Float16 h = (_Float16)x;
        hv[j] = h;
        lv[j] = (_Float16)(x - (float)h);
    }
    ((half8*)hi)[tid] = hv;
    ((half8*)lo)[tid] = lv;
}

// permuted-W2 f16 HI ONLY: Bp[h*256+k, c] = W2[k, h*256+c]; K=1024, N=256
__global__ __launch_bounds__(256) void splitB2_f16s_kernel(const float* __restrict__ W2,
                                                           _Float16* __restrict__ hi) {
    int tid = blockIdx.x * 256 + threadIdx.x;
    const int NG = 16;
    int total = (1024 >> 5) * NG * 64;   // 32768
    if (tid >= total) return;
    int lane = tid & 63;
    int rc = tid >> 6;
    int g = rc % NG, c = rc / NG;
    int n = g * 16 + (lane & 15);
    int kk = c * 32 + (lane >> 4) * 8;
    half8 hv;
#pragma unroll
    for (int j = 0; j < 8; ++j) {
        int kg = kk + j;
        int h = kg >> 8, k = kg & 255;
        hv[j] = (_Float16)W2[(size_t)k * 1024 + h * 256 + n];
    }
    ((half8*)hi)[tid] = hv;
}

// ---------------- MFMA GEMMs, N=256: barrier-free, row-major A ----------------
// block: 64 rows x 256 cols; wave w owns cols [w*64,(w+1)*64).
// A read row-major with per-lane fragment address: lane l of tile mt reads
// A[bm+mt*16+(l&15)][c*32+(l>>4)*8 ..+8] (16B; wave = 16 full 64B lines).
// B fragment-order (coalesced 1KB). No LDS, no barriers.
// Fused elr epilogue (alv!=null): from fp32 acc, pre-quantization.

__device__ inline floatx4 mfma16(short8 a, short8 b, floatx4 c) {
    return __builtin_amdgcn_mfma_f32_16x16x32_bf16(a, b, c, 0, 0, 0);
}
__device__ inline floatx4 mfma16h(half8 a, half8 b, floatx4 c) {
    return __builtin_amdgcn_mfma_f32_16x16x32_f16(a, b, c, 0, 0, 0);
}

// bf16-pair A x bf16-pair B (3-MFMA). Layer 0 (A = row-major feat split).
__global__ __launch_bounds__(256) void gemm_n256l(const short* __restrict__ Ahi,
                                                  const short* __restrict__ Alo,
                                                  const short* __restrict__ Bh,
                                                  const short* __restrict__ Bl,
                                                  _Float16* __restrict__ Cf,
                                                  const float* __restrict__ alv,
                                                  const float* __restrict__ arv,
                                                  float* __restrict__ elo,
                                                  float* __restrict__ ero,
                                                  int M, int K) {
    int KC = K >> 5;
    int t = threadIdx.x;
    int lane = t & 63;
    int w = t >> 6;
    int bm = blockIdx.x * 64;
    int g0 = w * 4;
    const short8* pBh = (const short8*)Bh;
    const short8* pBl = (const short8*)Bl;

    // per-tile A fragment base pointers (row-major, clamped rows)
    const short* pAh_[4];
    const short* pAl_[4];
#pragma unroll
    for (int mt = 0; mt < 4; ++mt) {
        int r = bm + mt * 16 + (lane & 15);
        if (r >= M) r = M - 1;                    // junk rows never stored
        pAh_[mt] = Ahi + (size_t)r * K + ((lane >> 4) << 3);
        pAl_[mt] = Alo + (size_t)r * K + ((lane >> 4) << 3);
    }

    floatx4 acc[4][4] = {};

    for (int c = 0; c < KC; ++c) {
        short8 ah[4], al4[4], bh[4], bl[4];
#pragma unroll
        for (int mt = 0; mt < 4; ++mt) {
            ah[mt] = *(const short8*)(pAh_[mt] + c * 32);
            al4[mt] = *(const short8*)(pAl_[mt] + c * 32);
        }
#pragma unroll
        for (int g = 0; g < 4; ++g) {
            size_t ib = ((size_t)c * 16 + g0 + g) * 64 + lane;
            bh[g] = pBh[ib];
            bl[g] = pBl[ib];
        }
#pragma unroll
        for (int mt = 0; mt < 4; ++mt) {
#pragma unroll
            for (int g = 0; g < 4; ++g) {
                acc[mt][g] = mfma16(ah[mt], bh[g], acc[mt][g]);
                acc[mt][g] = mfma16(al4[mt], bh[g], acc[mt][g]);
                acc[mt][g] = mfma16(ah[mt], bl[g], acc[mt][g]);
            }
        }
    }

    // C/D layout: col = lane&15, row = (lane>>4)*4 + reg
    int rowb = bm + (lane >> 4) * 4;
    int colb = w * 64 + (lane & 15);
#pragma unroll
    for (int mt = 0; mt < 4; ++mt) {
#pragma unroll
        for (int r = 0; r < 4; ++r) {
            int rr = rowb + mt * 16 + r;
            if (rr < M) {
#pragma unroll
                for (int g = 0; g < 4; ++g) {
                    Cf[(size_t)rr * 256 + colb + g * 16] = (_Float16)acc[mt][g][r];
                }
            }
        }
    }

    // fused elr: el[rr,w] = sum_f z[rr, w*64+f]*alv[w*64+f] (f = (lane&15)+g*16)
    if (alv) {
        float alr[4], arr_[4];
#pragma unroll
        for (int g = 0; g < 4; ++g) {
            int f = w * 64 + (lane & 15) + g * 16;
            alr[g] = alv[f];
            arr_[g] = arv[f];
        }
#pragma unroll
        for (int mt = 0; mt < 4; ++mt) {
#pragma unroll
            for (int r = 0; r < 4; ++r) {
                float se = acc[mt][0][r] * alr[0] + acc[mt][1][r] * alr[1] +
                           acc[mt][2][r] * alr[2] + acc[mt][3][r] * alr[3];
                float sr = acc[mt][0][r] * arr_[0] + acc[mt][1][r] * arr_[1] +
                           acc[mt][2][r] * arr_[2] + acc[mt][3][r] * arr_[3];
                se += __shfl_xor(se, 1); se += __shfl_xor(se, 2);
                se += __shfl_xor(se, 4); se += __shfl_xor(se, 8);
                sr += __shfl_xor(sr, 1); sr += __shfl_xor(sr, 2);
                sr += __shfl_xor(sr, 4); sr += __shfl_xor(sr, 8);
                int rr = rowb + mt * 16 + r;
                if ((lane & 15) == 0 && rr < M) {
                    elo[rr * 4 + w] = se;
                    ero[rr * 4 + w] = sr;
                }
            }
        }
    }
}

// single-f16 A (row-major) x f16 B (pair if Bl!=null, else single).
__global__ __launch_bounds__(256) void gemm_f16_n256(const _Float16* __restrict__ A,
                                                     const _Float16* __restrict__ Bh,
                                                     const _Float16* __restrict__ Bl,
                                                     const float* __restrict__ bias4,
                                                     float* __restrict__ C,
                                                     _Float16* __restrict__ Cf,
                                                     const float* __restrict__ alv,
                                                     const float* __restrict__ arv,
                                                     float* __restrict__ elo,
                                                     float* __restrict__ ero,
                                                     int M, int K) {
    int KC = K >> 5;
    int t = threadIdx.x;
    int lane = t & 63;
    int w = t >> 6;
    int bm = blockIdx.x * 64;
    int g0 = w * 4;
    const half8* pBh = (const half8*)Bh;
    const half8* pBl = (const half8*)Bl;
    bool dual = (Bl != nullptr);

    const _Float16* pA_[4];
#pragma unroll
    for (int mt = 0; mt < 4; ++mt) {
        int r = bm + mt * 16 + (lane & 15);
        if (r >= M) r = M - 1;                    // junk rows never stored
        pA_[mt] = A + (size_t)r * K + ((lane >> 4) << 3);
    }

    floatx4 acc[4][4] = {};

    for (int c = 0; c < KC; ++c) {
        half8 a[4], bh[4], bl[4];
#pragma unroll
        for (int mt = 0; mt < 4; ++mt) {
            a[mt] = *(const half8*)(pA_[mt] + c * 32);
        }
#pragma unroll
        for (int g = 0; g < 4; ++g) {
            bh[g] = pBh[((size_t)c * 16 + g0 + g) * 64 + lane];
        }
        if (dual) {
#pragma unroll
            for (int g = 0; g < 4; ++g) {
                bl[g] = pBl[((size_t)c * 16 + g0 + g) * 64 + lane];
            }
        }
#pragma unroll
        for (int mt = 0; mt < 4; ++mt) {
#pragma unroll
            for (int g = 0; g < 4; ++g) {
                acc[mt][g] = mfma16h(a[mt], bh[g], acc[mt][g]);
            }
            if (dual) {
#pragma unroll
                for (int g = 0; g < 4; ++g) {
                    acc[mt][g] = mfma16h(a[mt], bl[g], acc[mt][g]);
                }
            }
        }
    }

    // C/D layout: col = lane&15, row = (lane>>4)*4 + reg
    int rowb = bm + (lane >> 4) * 4;
    int colb = w * 64 + (lane & 15);
#pragma unroll
    for (int mt = 0; mt < 4; ++mt) {
#pragma unroll
        for (int r = 0; r < 4; ++r) {
            int rr = rowb + mt * 16 + r;
            if (rr < M) {
#pragma unroll
                for (int g = 0; g < 4; ++g) {
                    int col = colb + g * 16;
                    float v = acc[mt][g][r];
                    if (bias4) {
                        v = 0.25f * (v + bias4[col] + bias4[col + 256] +
                                     bias4[col + 512] + bias4[col + 768]);
                    }
                    if (Cf) Cf[(size_t)rr * 256 + col] = (_Float16)v;
                    else    C[(size_t)rr * 256 + col] = v;
                }
            }
        }
    }

    // fused elr from fp32 acc
    if (alv) {
        float alr[4], arr_[4];
#pragma unroll
        for (int g = 0; g < 4; ++g) {
            int f = w * 64 + (lane & 15) + g * 16;
            alr[g] = alv[f];
            arr_[g] = arv[f];
        }
#pragma unroll
        for (int mt = 0; mt < 4; ++mt) {
#pragma unroll
            for (int r = 0; r < 4; ++r) {
                float se = acc[mt][0][r] * alr[0] + acc[mt][1][r] * alr[1] +
                           acc[mt][2][r] * alr[2] + acc[mt][3][r] * alr[3];
                float sr = acc[mt][0][r] * arr_[0] + acc[mt][1][r] * arr_[1] +
                           acc[mt][2][r] * arr_[2] + acc[mt][3][r] * arr_[3];
                se += __shfl_xor(se, 1); se += __shfl_xor(se, 2);
                se += __shfl_xor(se, 4); se += __shfl_xor(se, 8);
                sr += __shfl_xor(sr, 1); sr += __shfl_xor(sr, 2);
                sr += __shfl_xor(sr, 4); sr += __shfl_xor(sr, 8);
                int rr = rowb + mt * 16 + r;
                if ((lane & 15) == 0 && rr < M) {
                    elo[rr * 4 + w] = se;
                    ero[rr * 4 + w] = sr;
                }
            }
        }
    }
}

// ---------------- attention score parts (layer 2) ----------------

// val[h*256+k] = sum_j W2[k,h*256+j]*al2[h,j] ; var likewise with ar2
__global__ __launch_bounds__(256) void proj_av_kernel(const float* __restrict__ W2,
                                                      const float* __restrict__ al2,
                                                      const float* __restrict__ ar2,
                                                      float* __restrict__ val,
                                                      float* __restrict__ var_) {
    int gid = blockIdx.x * 256 + threadIdx.x;
    int w = gid >> 6;
    int lane = threadIdx.x & 63;
    if (w >= 1024) return;
    int h = w >> 8, k = w & 255;
    const float* wrow = W2 + (size_t)k * 1024 + h * 256;
    const float* ap = al2 + h * 256;
    const float* rp = ar2 + h * 256;
    float sv = 0.f, sr = 0.f;
    for (int j = lane; j < 256; j += 64) {
        float x = wrow[j];
        sv += x * ap[j];
        sr += x * rp[j];
    }
#pragma unroll
    for (int off = 32; off > 0; off >>= 1) {
        sv += __shfl_down(sv, off);
        sr += __shfl_down(sr, off);
    }
    if (lane == 0) { val[w] = sv; var_[w] = sr; }
}

// el[n,h] = h1[n,:]·val[h,:], er likewise (h1 fp16 row-major)
__global__ __launch_bounds__(256) void elr2_kernel(const _Float16* __restrict__ h1,
                                                   const float* __restrict__ val,
                                                   const float* __restrict__ var_,
                                                   float* __restrict__ el,
                                                   float* __restrict__ er) {
    int gid = blockIdx.x * 256 + threadIdx.x;
    int w = gid >> 6;
    int lane = threadIdx.x & 63;
    if (w >= NN * 4) return;
    int n = w >> 2, h = w & 3;
    const _Float16* hr = h1 + (size_t)n * 256;
    const float* vp = val + h * 256;
    const float* rp = var_ + h * 256;
    float se = 0.f, sr = 0.f;
    for (int k = lane; k < 256; k += 64) {
        float x = (float)hr[k];
        se += x * vp[k];
        sr += x * rp[k];
    }
#pragma unroll
    for (int off = 32; off > 0; off >>= 1) {
        se += __shfl_down(se, off);
        sr += __shfl_down(sr, off);
    }
    if (lane == 0) { el[w] = se; er[w] = sr; }
}

// ---------------- aggregation: 1-wave blocks, half4 loads ----------------
// Block = 64 lanes = one node. Lane l owns cols 4l..4l+3 (head h = l>>4).
// p-phase: chunk = 16 edges x 4 heads = 64 lanes; den via shfl_xor.
// All outputs row-major (contiguous half4 stores, coalesced).

// z-gather (layers 0 & 1): elu epilogue, f16 out [N,256].
__global__ __launch_bounds__(64) void agg_z64_kernel(const _Float16* __restrict__ z,
                                                     const float* __restrict__ el,
                                                     const float* __restrict__ er,
                                                     const int* __restrict__ offs,
                                                     const int* __restrict__ psrc,
                                                     const float* __restrict__ bias,
                                                     _Float16* __restrict__ out) {
    int n = blockIdx.x;
    int l = threadIdx.x;
    __shared__ float p_lds[16][4];
    __shared__ int src_lds[16];
    __shared__ float den_lds[4];
    if (l < 4) den_lds[l] = 0.f;
    int e_local = l >> 2, hh = l & 3;
    int h = l >> 4;
    float er_n = er[n * 4 + hh];
    int beg = offs[n], end = offs[n + 1];
    float a0 = 0.f, a1 = 0.f, a2 = 0.f, a3 = 0.f;
    for (int base = beg; base < end; base += 16) {
        int cnt = min(16, end - base);
        __syncthreads();
        float p = 0.f;
        if (e_local < cnt) {
            int s = psrc[base + e_local];
            if (hh == 0) src_lds[e_local] = s;
            float sc = el[s * 4 + hh] + er_n;
            sc = (sc > 0.f) ? sc : 0.2f * sc;
            p = __expf(sc);
            p_lds[e_local][hh] = p;
        }
        float d = p;
        d += __shfl_xor(d, 4);  d += __shfl_xor(d, 8);
        d += __shfl_xor(d, 16); d += __shfl_xor(d, 32);
        if (l < 4) den_lds[l] += d;
        __syncthreads();
        for (int e = 0; e < cnt; ++e) {
            half4 v = *(const half4*)(z + (size_t)src_lds[e] * 256 + (l << 2));
            float pe = p_lds[e][h];
            a0 += pe * (float)v[0];
            a1 += pe * (float)v[1];
            a2 += pe * (float)v[2];
            a3 += pe * (float)v[3];
        }
    }
    __syncthreads();
    float rd = 1.f / fmaxf(den_lds[h], 1e-9f);
    float vals[4] = {a0, a1, a2, a3};
    half4 o;
#pragma unroll
    for (int j = 0; j < 4; ++j) {
        float x = vals[j] * rd + bias[(l << 2) + j];
        x = (x > 0.f) ? x : (__expf(x) - 1.f);
        o[j] = (_Float16)x;
    }
    *(half4*)(out + (size_t)n * 256 + (l << 2)) = o;
}

// layer-2 aggregation of h1 (fp16) -> row-major f16 [N,1024] (final GEMM A).
__global__ __launch_bounds__(64) void aggH_64_kernel(const _Float16* __restrict__ h1,
                                                     const float* __restrict__ el,
                                                     const float* __restrict__ er,
                                                     const int* __restrict__ offs,
                                                     const int* __restrict__ psrc,
                                                     _Float16* __restrict__ oA) {
    int n = blockIdx.x;
    int l = threadIdx.x;
    __shared__ __align__(16) float p_lds[16][4];
    __shared__ int src_lds[16];
    __shared__ float den_lds[4];
    if (l < 4) den_lds[l] = 0.f;
    int e_local = l >> 2, hh = l & 3;
    float er_n = er[n * 4 + hh];
    int beg = offs[n], end = offs[n + 1];
    float acc[4][4] = {};   // [head][colj]
    for (int base = beg; base < end; base += 16) {
        int cnt = min(16, end - base);
        __syncthreads();
        float p = 0.f;
        if (e_local < cnt) {
            int s = psrc[base + e_local];
            if (hh == 0) src_lds[e_local] = s;
            float sc = el[s * 4 + hh] + er_n;
            sc = (sc > 0.f) ? sc : 0.2f * sc;
            p = __expf(sc);
            p_lds[e_local][hh] = p;
        }
        float d = p;
        d += __shfl_xor(d, 4);  d += __shfl_xor(d, 8);
        d += __shfl_xor(d, 16); d += __shfl_xor(d, 32);
        if (l < 4) den_lds[l] += d;
        __syncthreads();
        for (int e = 0; e < cnt; ++e) {
            half4 v = *(const half4*)(h1 + (size_t)src_lds[e] * 256 + (l << 2));
            float vf0 = (float)v[0], vf1 = (float)v[1];
            float vf2 = (float)v[2], vf3 = (float)v[3];
            floatx4 pv = *(const floatx4*)&p_lds[e][0];
#pragma unroll
            for (int hd = 0; hd < 4; ++hd) {
                acc[hd][0] += pv[hd] * vf0;
                acc[hd][1] += pv[hd] * vf1;
                acc[hd][2] += pv[hd] * vf2;
                acc[hd][3] += pv[hd] * vf3;
            }
        }
    }
    __syncthreads();
    size_t base_o = (size_t)n * 1024 + (l << 2);
#pragma unroll
    for (int hd = 0; hd < 4; ++hd) {
        float rd = 1.f / fmaxf(den_lds[hd], 1e-9f);
        half4 o;
#pragma unroll
        for (int j = 0; j < 4; ++j) o[j] = (_Float16)(acc[hd][j] * rd);
        *(half4*)(oA + base_o + hd * 256) = o;
    }
}

// ---------------- launch ----------------

extern "C" void kernel_launch(void* const* d_in, const int* in_sizes, int n_in,
                              void* d_out, int out_size, void* d_ws, size_t ws_size,
                              hipStream_t stream) {
    const float* feat = (const float*)d_in[0];
    const float* W0 = (const float*)d_in[1];
    const float* al0 = (const float*)d_in[2];
    const float* ar0 = (const float*)d_in[3];
    const float* b0 = (const float*)d_in[4];
    const float* W1 = (const float*)d_in[5];
    const float* al1 = (const float*)d_in[6];
    const float* ar1 = (const float*)d_in[7];
    const float* b1 = (const float*)d_in[8];
    const float* W2 = (const float*)d_in[9];
    const float* al2 = (const float*)d_in[10];
    const float* ar2 = (const float*)d_in[11];
    const float* b2 = (const float*)d_in[12];
    const int* src = (const int*)d_in[13];
    const int* dst = (const int*)d_in[14];
    float* out = (float*)d_out;

    // ---- workspace layout (~262.5 MB), time-multiplexed big slots ----
    float* slotA = (float*)d_ws;
    _Float16* zh = (_Float16*)slotA;                      // [N,256] fp16 (z slot)
    short* feathi = (short*)(slotA + (size_t)NN * 256);   // 50000*128 shorts (rm)
    short* featlo = feathi + (size_t)NN * 128;
    _Float16* Af16 = (_Float16*)slotA;                    // [N,1024] f16 (rm, layer 2)
    float* slotB = slotA + (size_t)NN * 1024;
    _Float16* h0f = (_Float16*)slotB;                     // [N,256] f16 (rm)
    _Float16* h1h = (_Float16*)slotB;                     // [N,256] f16 (rm, layer 2)
    float* el = slotB + (size_t)NN * 256;                 // 200000
    float* er = el + (size_t)NN * NH_HEADS;               // 200000
    int* deg = (int*)(er + (size_t)NN * NH_HEADS);        // 50000
    int* offs = deg + NN;                                 // 50001 (+1 pad)
    int* cursor = offs + NN + 2;                          // 50000
    int* bsums = cursor + NN;                             // 256
    int* boffs = bsums + 256;                             // 256
    int* psrc = boffs + 256;                              // 800000 (+2 pad)
    short* Bh = (short*)(psrc + NE + 2);                  // 262144 shorts / half8s
    short* Bl = Bh + 262144;                              // 262144 shorts
    float* val = (float*)(Bl + 262144);                   // 1024
    float* var_ = val + 1024;                             // 1024

    // ---- CSR build (by dst) ----
    hipMemsetAsync(deg, 0, NN * sizeof(int), stream);
    hist_kernel<<<(NE + 255) / 256, 256, 0, stream>>>(dst, deg, NE);
    int nb = (NN + 255) / 256;
    scan_block_kernel<<<nb, 256, 0, stream>>>(deg, offs, bsums, NN);
    scan_sums_kernel<<<1, 256, 0, stream>>>(bsums, boffs, nb);
    add_offs_kernel<<<nb, 256, 0, stream>>>(offs, boffs, cursor, NN, NE);
    scatter_kernel<<<(NE + 255) / 256, 256, 0, stream>>>(src, dst, cursor, psrc, NE);

    int mb64 = (NN + 63) / 64; // 782

    // ---- layer 0: 128 -> 4x64, elu (barrier-free bf16-pair GEMM; z fp16) ----
    splitA_rm<<<(NN * 128 / 8 + 255) / 256, 256, 0, stream>>>(feat, feathi, featlo, NN * 128 / 8);
    splitB_kernel<<<(4096 + 255) / 256, 256, 0, stream>>>(W0, Bh, Bl, 128, 256);
    gemm_n256l<<<mb64, 256, 0, stream>>>(feathi, featlo, Bh, Bl, zh,
                                         al0, ar0, el, er, NN, 128);
    agg_z64_kernel<<<NN, 64, 0, stream>>>(zh, el, er, offs, psrc, b0, h0f);

    // ---- layer 1: 256 -> 4x64, elu (barrier-free f16 GEMM, B pair) ----
    splitB_f16_kernel<<<(8192 + 255) / 256, 256, 0, stream>>>(W1, (_Float16*)Bh,
                                                              (_Float16*)Bl, 256, 256);
    gemm_f16_n256<<<mb64, 256, 0, stream>>>(h0f, (const _Float16*)Bh, (const _Float16*)Bl,
                                            nullptr, nullptr, zh, al1, ar1, el, er,
                                            NN, 256);
    agg_z64_kernel<<<NN, 64, 0, stream>>>(zh, el, er, offs, psrc, b1, h1h);

    // ---- layer 2: score from aggregated h1, then f16 K=1024 projection ----
    proj_av_kernel<<<256, 256, 0, stream>>>(W2, al2, ar2, val, var_);
    elr2_kernel<<<NN, 256, 0, stream>>>(h1h, val, var_, el, er);
    aggH_64_kernel<<<NN, 64, 0, stream>>>(h1h, el, er, offs, psrc, Af16);
    splitB2_f16s_kernel<<<(32768 + 255) / 256, 256, 0, stream>>>(W2, (_Float16*)Bh);
    gemm_f16_n256<<<mb64, 256, 0, stream>>>(Af16, (const _Float16*)Bh, nullptr,
                                            b2, out, nullptr, nullptr, nullptr,
                                            nullptr, nullptr, NN, 1024);
}

// Round 19
// 571.519 us; speedup vs baseline: 1.1699x; 1.0822x over previous
//
#include <hip/hip_runtime.h>
#include <hip/hip_bf16.h>

// GAT: 3 layers. N=50000 nodes, E=800000 edges, H=4 heads.
// R20: 1-wave half4 gathers -> 615us. R21: W2 single-f16 final GEMM ->
// 592.7us (BEST). R22 (668us): fragment-order producer writes doubled
// aggH write traffic. R25 (618us): barrier-free row-major-A GEMM lost
// A-sharing (4x L2 A-traffic) -> slower than R21's LDS version.
// Lesson: R21's staged GEMM is the best inner loop; its limiter is
// OCCUPANCY: 782 blocks x 4 waves = 3.05 waves/SIMD (grid-limited),
// so all resident waves drain vmcnt(0)+barrier together.
// R26: full revert to R21 + N-split=2 on the FINAL GEMM only
// (gemm_f16_ns2: 64x128 output/block, blockIdx.y = col-half, LDS-staged
// shared A, acc[4][2]) -> 6.1 waves/SIMD. A L2-read doubles (~3us at
// 35TB/s) - cheap. L0/L1 GEMMs + all else byte-identical to R21.
// NO arithmetic change: absmax must stay exactly 4.882812e-4.

#define NN 50000
#define NE 800000
#define NH_HEADS 4

typedef __attribute__((ext_vector_type(8))) short short8;
typedef __attribute__((ext_vector_type(8))) _Float16 half8;
typedef __attribute__((ext_vector_type(4))) _Float16 half4;
typedef __attribute__((ext_vector_type(4))) float floatx4;

__device__ inline float bf2f(short s) {
    union { unsigned u; float f; } v; v.u = ((unsigned)(unsigned short)s) << 16;
    return v.f;
}
__device__ inline short f2bf_rne(float x) {
    union { float f; unsigned u; } v; v.f = x;
    unsigned r = v.u + 0x7fff + ((v.u >> 16) & 1);
    return (short)(r >> 16);
}
// truncation hi/lo split: hi = trunc16(x), lo = trunc16(x - hi)
__device__ inline void split1(float x, short& h, short& l) {
    union { float f; unsigned u; } v; v.f = x;
    h = (short)(v.u >> 16);
    union { float f; unsigned u; } rv; rv.f = v.f - bf2f(h);
    l = (short)(rv.u >> 16);
}

// async 16B/lane global->LDS; lds base must be wave-uniform (dest = base + lane*16)
__device__ inline void load_lds16(const void* g, void* l) {
    __builtin_amdgcn_global_load_lds(
        (const __attribute__((address_space(1))) void*)g,
        (__attribute__((address_space(3))) void*)l, 16, 0, 0);
}

// ---------------- CSR build ----------------

__global__ void hist_kernel(const int* __restrict__ dst, int* __restrict__ deg, int E) {
    int e = blockIdx.x * 256 + threadIdx.x;
    if (e < E) atomicAdd(&deg[dst[e]], 1);
}

__global__ void scan_block_kernel(const int* __restrict__ deg, int* __restrict__ offs,
                                  int* __restrict__ bsums, int n) {
    __shared__ int s[256];
    int tid = threadIdx.x;
    int i = blockIdx.x * 256 + tid;
    int v = (i < n) ? deg[i] : 0;
    s[tid] = v;
    __syncthreads();
    for (int off = 1; off < 256; off <<= 1) {
        int x = (tid >= off) ? s[tid - off] : 0;
        __syncthreads();
        s[tid] += x;
        __syncthreads();
    }
    if (i < n) offs[i] = s[tid] - v;
    if (tid == 255) bsums[blockIdx.x] = s[255];
}

__global__ void scan_sums_kernel(const int* __restrict__ bsums, int* __restrict__ boffs, int nb) {
    __shared__ int s[256];
    int tid = threadIdx.x;
    int v = (tid < nb) ? bsums[tid] : 0;
    s[tid] = v;
    __syncthreads();
    for (int off = 1; off < 256; off <<= 1) {
        int x = (tid >= off) ? s[tid - off] : 0;
        __syncthreads();
        s[tid] += x;
        __syncthreads();
    }
    boffs[tid] = s[tid] - v;
}

__global__ void add_offs_kernel(int* __restrict__ offs, const int* __restrict__ boffs,
                                int* __restrict__ cursor, int n, int total) {
    int i = blockIdx.x * 256 + threadIdx.x;
    if (i < n) {
        int o = offs[i] + boffs[blockIdx.x];
        offs[i] = o;
        cursor[i] = o;
    }
    if (i == 0) offs[n] = total;
}

__global__ void scatter_kernel(const int* __restrict__ src, const int* __restrict__ dst,
                               int* __restrict__ cursor, int* __restrict__ psrc, int E) {
    int e = blockIdx.x * 256 + threadIdx.x;
    if (e < E) {
        int p = atomicAdd(&cursor[dst[e]], 1);
        psrc[p] = src[e];
    }
}

// ---------------- A (row-major fp32) -> row-major bf16 hi/lo ----------------

__global__ __launch_bounds__(256) void splitA_rm(const float* __restrict__ A,
                                                 short* __restrict__ hi,
                                                 short* __restrict__ lo,
                                                 int total8) {
    int tid = blockIdx.x * 256 + threadIdx.x;
    if (tid >= total8) return;
    const float* p = A + (size_t)tid * 8;
    float4 x0 = ((const float4*)p)[0];
    float4 x1 = ((const float4*)p)[1];
    float xs[8] = {x0.x, x0.y, x0.z, x0.w, x1.x, x1.y, x1.z, x1.w};
    short8 hv, lv;
#pragma unroll
    for (int j = 0; j < 8; ++j) { short h, l; split1(xs[j], h, l); hv[j] = h; lv[j] = l; }
    ((short8*)hi)[tid] = hv;
    ((short8*)lo)[tid] = lv;
}

// ---------------- B -> hi/lo in MFMA B-fragment order ----------------
// offset (x8) = (c*(N/16)+g)*64 + lane ; lane=(n&15)+16*((k&31)>>3), j=k&7

__global__ __launch_bounds__(256) void splitB_kernel(const float* __restrict__ B,
                                                     short* __restrict__ hi,
                                                     short* __restrict__ lo,
                                                     int K, int N) {
    int tid = blockIdx.x * 256 + threadIdx.x;
    int NG = N >> 4;
    int total = (K >> 5) * NG * 64;
    if (tid >= total) return;
    int lane = tid & 63;
    int rc = tid >> 6;
    int g = rc % NG, c = rc / NG;
    int n = g * 16 + (lane & 15);
    int k = c * 32 + (lane >> 4) * 8;
    short8 hv, lv;
#pragma unroll
    for (int j = 0; j < 8; ++j) {
        float x = B[(size_t)(k + j) * N + n];
        short h = f2bf_rne(x);
        hv[j] = h;
        lv[j] = f2bf_rne(x - bf2f(h));
    }
    ((short8*)hi)[tid] = hv;
    ((short8*)lo)[tid] = lv;
}

// f16 hi/lo variant (for W1)
__global__ __launch_bounds__(256) void splitB_f16_kernel(const float* __restrict__ B,
                                                         _Float16* __restrict__ hi,
                                                         _Float16* __restrict__ lo,
                                                         int K, int N) {
    int tid = blockIdx.x * 256 + threadIdx.x;
    int NG = N >> 4;
    int total = (K >> 5) * NG * 64;
    if (tid >= total) return;
    int lane = tid & 63;
    int rc = tid >> 6;
    int g = rc % NG, c = rc / NG;
    int n = g * 16 + (lane & 15);
    int k = c * 32 + (lane >> 4) * 8;
    half8 hv, lv;
#pragma unroll
    for (int j = 0; j < 8; ++j) {
        float x = B[(size_t)(k + j) * N + n];
        _Float16 h = (_Float16)x;
        hv[j] = h;
        lv[j] = (_Float16)(x - (float)h);
    }
    ((half8*)hi)[tid] = hv;
    ((half8*)lo)[tid] = lv;
}

// permuted-W2 f16 HI ONLY: Bp[h*256+k, c] = W2[k, h*256+c]; K=1024, N=256
// (final GEMM output is head-mean: x0.25 scales W2-quant error to ~1.5e-4)
__global__ __launch_bounds__(256) void splitB2_f16s_kernel(const float* __restrict__ W2,
                                                           _Float16* __restrict__ hi) {
    int tid = blockIdx.x * 256 + threadIdx.x;
    const int NG = 16;
    int total = (1024 >> 5) * NG * 64;   // 32768
    if (tid >= total) return;
    int lane = tid & 63;
    int rc = tid >> 6;
    int g = rc % NG, c = rc / NG;
    int n = g * 16 + (lane & 15);
    int kk = c * 32 + (lane >> 4) * 8;
    half8 hv;
#pragma unroll
    for (int j = 0; j < 8; ++j) {
        int kg = kk + j;
        int h = kg >> 8, k = kg & 255;
        hv[j] = (_Float16)W2[(size_t)k * 1024 + h * 256 + n];
    }
    ((half8*)hi)[tid] = hv;
}

// ---------------- MFMA GEMMs, N=256, A via async LDS staging ----------------
// block: 64 rows x 256 cols; wave w owns cols [w*64,(w+1)*64).
// Fused elr epilogue (alv!=null): from fp32 acc, pre-quantization.

__device__ inline floatx4 mfma16(short8 a, short8 b, floatx4 c) {
    return __builtin_amdgcn_mfma_f32_16x16x32_bf16(a, b, c, 0, 0, 0);
}
__device__ inline floatx4 mfma16h(half8 a, half8 b, floatx4 c) {
    return __builtin_amdgcn_mfma_f32_16x16x32_f16(a, b, c, 0, 0, 0);
}

// bf16-pair A x bf16-pair B (3-MFMA). Layer 0 (A = fp32 feat split).
__global__ __launch_bounds__(256) void gemm_n256l(const short* __restrict__ Ahi,
                                                  const short* __restrict__ Alo,
                                                  const short* __restrict__ Bh,
                                                  const short* __restrict__ Bl,
                                                  _Float16* __restrict__ Cf,
                                                  const float* __restrict__ alv,
                                                  const float* __restrict__ arv,
                                                  float* __restrict__ elo,
                                                  float* __restrict__ ero,
                                                  int M, int K) {
    int KC = K >> 5;
    __shared__ short AhL[2048];   // 4 m-tiles x 64 lanes x 8 shorts = 4 KB
    __shared__ short AlL[2048];
    int t = threadIdx.x;
    int lane = t & 63;
    int w = t >> 6;
    int bm = blockIdx.x * 64;
    int g0 = w * 4;
    const short8* pBh = (const short8*)Bh;
    const short8* pBl = (const short8*)Bl;

    floatx4 acc[4][4] = {};

    int row = bm + (w << 4) + (lane & 15);
    if (row >= M) row = M - 1;                    // clamp: junk rows never stored
    const short* gh = Ahi + (size_t)row * K + ((lane >> 4) << 3);
    const short* gl = Alo + (size_t)row * K + ((lane >> 4) << 3);
    short* lh = AhL + w * 512;                    // wave-uniform LDS base
    short* ll = AlL + w * 512;

    for (int c = 0; c < KC; ++c) {
        load_lds16(gh + (size_t)c * 32, lh);
        load_lds16(gl + (size_t)c * 32, ll);
        short8 bh[4], bl[4];
#pragma unroll
        for (int g = 0; g < 4; ++g) {
            bh[g] = pBh[((size_t)c * 16 + g0 + g) * 64 + lane];
            bl[g] = pBl[((size_t)c * 16 + g0 + g) * 64 + lane];
        }
        __syncthreads();   // drains vmcnt: LDS staged, B regs ready
#pragma unroll
        for (int mt = 0; mt < 4; ++mt) {
            short8 ah = *(const short8*)(AhL + mt * 512 + lane * 8);
            short8 al = *(const short8*)(AlL + mt * 512 + lane * 8);
#pragma unroll
            for (int g = 0; g < 4; ++g) {
                acc[mt][g] = mfma16(ah, bh[g], acc[mt][g]);
                acc[mt][g] = mfma16(al, bh[g], acc[mt][g]);
                acc[mt][g] = mfma16(ah, bl[g], acc[mt][g]);
            }
        }
        __syncthreads();   // all LDS reads done before next overwrite
    }

    // C/D layout: col = lane&15, row = (lane>>4)*4 + reg
    int rowb = bm + (lane >> 4) * 4;
    int colb = w * 64 + (lane & 15);
#pragma unroll
    for (int mt = 0; mt < 4; ++mt) {
#pragma unroll
        for (int r = 0; r < 4; ++r) {
            int rr = rowb + mt * 16 + r;
            if (rr < M) {
#pragma unroll
                for (int g = 0; g < 4; ++g) {
                    Cf[(size_t)rr * 256 + colb + g * 16] = (_Float16)acc[mt][g][r];
                }
            }
        }
    }

    // fused elr: el[rr,w] = sum_f z[rr, w*64+f]*alv[w*64+f] (f = (lane&15)+g*16)
    if (alv) {
        float alr[4], arr_[4];
#pragma unroll
        for (int g = 0; g < 4; ++g) {
            int f = w * 64 + (lane & 15) + g * 16;
            alr[g] = alv[f];
            arr_[g] = arv[f];
        }
#pragma unroll
        for (int mt = 0; mt < 4; ++mt) {
#pragma unroll
            for (int r = 0; r < 4; ++r) {
                float se = acc[mt][0][r] * alr[0] + acc[mt][1][r] * alr[1] +
                           acc[mt][2][r] * alr[2] + acc[mt][3][r] * alr[3];
                float sr = acc[mt][0][r] * arr_[0] + acc[mt][1][r] * arr_[1] +
                           acc[mt][2][r] * arr_[2] + acc[mt][3][r] * arr_[3];
                se += __shfl_xor(se, 1); se += __shfl_xor(se, 2);
                se += __shfl_xor(se, 4); se += __shfl_xor(se, 8);
                sr += __shfl_xor(sr, 1); sr += __shfl_xor(sr, 2);
                sr += __shfl_xor(sr, 4); sr += __shfl_xor(sr, 8);
                int rr = rowb + mt * 16 + r;
                if ((lane & 15) == 0 && rr < M) {
                    elo[rr * 4 + w] = se;
                    ero[rr * 4 + w] = sr;
                }
            }
        }
    }
}

// single-f16 A x f16-pair B (2-MFMA). Layer 1 (A=h0 f16, K=256), elr fused.
__global__ __launch_bounds__(256) void gemm_f16_n256(const _Float16* __restrict__ A,
                                                     const _Float16* __restrict__ Bh,
                                                     const _Float16* __restrict__ Bl,
                                                     _Float16* __restrict__ Cf,
                                                     const float* __restrict__ alv,
                                                     const float* __restrict__ arv,
                                                     float* __restrict__ elo,
                                                     float* __restrict__ ero,
                                                     int M, int K) {
    int KC = K >> 5;
    __shared__ _Float16 AL[2048];   // 4 m-tiles x 64 lanes x 8 halves = 4 KB
    int t = threadIdx.x;
    int lane = t & 63;
    int w = t >> 6;
    int bm = blockIdx.x * 64;
    int g0 = w * 4;
    const half8* pBh = (const half8*)Bh;
    const half8* pBl = (const half8*)Bl;

    floatx4 acc[4][4] = {};

    int row = bm + (w << 4) + (lane & 15);
    if (row >= M) row = M - 1;                    // clamp: junk rows never stored
    const _Float16* gA = A + (size_t)row * K + ((lane >> 4) << 3);
    _Float16* lA = AL + w * 512;                  // wave-uniform LDS base

    for (int c = 0; c < KC; ++c) {
        load_lds16(gA + (size_t)c * 32, lA);
        half8 bh[4], bl[4];
#pragma unroll
        for (int g = 0; g < 4; ++g) {
            bh[g] = pBh[((size_t)c * 16 + g0 + g) * 64 + lane];
            bl[g] = pBl[((size_t)c * 16 + g0 + g) * 64 + lane];
        }
        __syncthreads();   // drains vmcnt: LDS staged, B regs ready
#pragma unroll
        for (int mt = 0; mt < 4; ++mt) {
            half8 a = *(const half8*)(AL + mt * 512 + lane * 8);
#pragma unroll
            for (int g = 0; g < 4; ++g) {
                acc[mt][g] = mfma16h(a, bh[g], acc[mt][g]);
                acc[mt][g] = mfma16h(a, bl[g], acc[mt][g]);
            }
        }
        __syncthreads();   // all LDS reads done before next overwrite
    }

    // C/D layout: col = lane&15, row = (lane>>4)*4 + reg
    int rowb = bm + (lane >> 4) * 4;
    int colb = w * 64 + (lane & 15);
#pragma unroll
    for (int mt = 0; mt < 4; ++mt) {
#pragma unroll
        for (int r = 0; r < 4; ++r) {
            int rr = rowb + mt * 16 + r;
            if (rr < M) {
#pragma unroll
                for (int g = 0; g < 4; ++g) {
                    Cf[(size_t)rr * 256 + colb + g * 16] = (_Float16)acc[mt][g][r];
                }
            }
        }
    }

    // fused elr from fp32 acc
    if (alv) {
        float alr[4], arr_[4];
#pragma unroll
        for (int g = 0; g < 4; ++g) {
            int f = w * 64 + (lane & 15) + g * 16;
            alr[g] = alv[f];
            arr_[g] = arv[f];
        }
#pragma unroll
        for (int mt = 0; mt < 4; ++mt) {
#pragma unroll
            for (int r = 0; r < 4; ++r) {
                float se = acc[mt][0][r] * alr[0] + acc[mt][1][r] * alr[1] +
                           acc[mt][2][r] * alr[2] + acc[mt][3][r] * alr[3];
                float sr = acc[mt][0][r] * arr_[0] + acc[mt][1][r] * arr_[1] +
                           acc[mt][2][r] * arr_[2] + acc[mt][3][r] * arr_[3];
                se += __shfl_xor(se, 1); se += __shfl_xor(se, 2);
                se += __shfl_xor(se, 4); se += __shfl_xor(se, 8);
                sr += __shfl_xor(sr, 1); sr += __shfl_xor(sr, 2);
                sr += __shfl_xor(sr, 4); sr += __shfl_xor(sr, 8);
                int rr = rowb + mt * 16 + r;
                if ((lane & 15) == 0 && rr < M) {
                    elo[rr * 4 + w] = se;
                    ero[rr * 4 + w] = sr;
                }
            }
        }
    }
}

// final projection, N-split=2: single-f16 A x single-f16 B, K=1024.
// block = 64 rows x 128 cols (blockIdx.y = col-half); wave w: g0=y*8+w*2.
// LDS-staged shared A (as above); grid 782x2 -> 6.1 waves/SIMD.
__global__ __launch_bounds__(256) void gemm_f16_ns2(const _Float16* __restrict__ A,
                                                    const _Float16* __restrict__ Bh,
                                                    const float* __restrict__ bias4,
                                                    float* __restrict__ C,
                                                    int M, int K) {
    int KC = K >> 5;
    __shared__ _Float16 AL[2048];   // 4 m-tiles x 64 lanes x 8 halves = 4 KB
    int t = threadIdx.x;
    int lane = t & 63;
    int w = t >> 6;
    int bm = blockIdx.x * 64;
    int g0 = blockIdx.y * 8 + w * 2;
    const half8* pBh = (const half8*)Bh;

    floatx4 acc[4][2] = {};

    int row = bm + (w << 4) + (lane & 15);
    if (row >= M) row = M - 1;                    // clamp: junk rows never stored
    const _Float16* gA = A + (size_t)row * K + ((lane >> 4) << 3);
    _Float16* lA = AL + w * 512;                  // wave-uniform LDS base

    for (int c = 0; c < KC; ++c) {
        load_lds16(gA + (size_t)c * 32, lA);
        half8 bh[2];
#pragma unroll
        for (int g = 0; g < 2; ++g) {
            bh[g] = pBh[((size_t)c * 16 + g0 + g) * 64 + lane];
        }
        __syncthreads();   // drains vmcnt: LDS staged, B regs ready
#pragma unroll
        for (int mt = 0; mt < 4; ++mt) {
            half8 a = *(const half8*)(AL + mt * 512 + lane * 8);
#pragma unroll
            for (int g = 0; g < 2; ++g) {
                acc[mt][g] = mfma16h(a, bh[g], acc[mt][g]);
            }
        }
        __syncthreads();   // all LDS reads done before next overwrite
    }

    // C/D layout: col = lane&15, row = (lane>>4)*4 + reg
    int rowb = bm + (lane >> 4) * 4;
    int colb = blockIdx.y * 128 + w * 32 + (lane & 15);
#pragma unroll
    for (int mt = 0; mt < 4; ++mt) {
#pragma unroll
        for (int r = 0; r < 4; ++r) {
            int rr = rowb + mt * 16 + r;
            if (rr < M) {
#pragma unroll
                for (int g = 0; g < 2; ++g) {
                    int col = colb + g * 16;
                    float v = acc[mt][g][r];
                    v = 0.25f * (v + bias4[col] + bias4[col + 256] +
                                 bias4[col + 512] + bias4[col + 768]);
                    C[(size_t)rr * 256 + col] = v;
                }
            }
        }
    }
}

// ---------------- attention score parts (layer 2) ----------------

// val[h*256+k] = sum_j W2[k,h*256+j]*al2[h,j] ; var likewise with ar2
__global__ __launch_bounds__(256) void proj_av_kernel(const float* __restrict__ W2,
                                                      const float* __restrict__ al2,
                                                      const float* __restrict__ ar2,
                                                      float* __restrict__ val,
                                                      float* __restrict__ var_) {
    int gid = blockIdx.x * 256 + threadIdx.x;
    int w = gid >> 6;
    int lane = threadIdx.x & 63;
    if (w >= 1024) return;
    int h = w >> 8, k = w & 255;
    const float* wrow = W2 + (size_t)k * 1024 + h * 256;
    const float* ap = al2 + h * 256;
    const float* rp = ar2 + h * 256;
    float sv = 0.f, sr = 0.f;
    for (int j = lane; j < 256; j += 64) {
        float x = wrow[j];
        sv += x * ap[j];
        sr += x * rp[j];
    }
#pragma unroll
    for (int off = 32; off > 0; off >>= 1) {
        sv += __shfl_down(sv, off);
        sr += __shfl_down(sr, off);
    }
    if (lane == 0) { val[w] = sv; var_[w] = sr; }
}

// el[n,h] = h1[n,:]·val[h,:], er likewise (h1 fp16)
__global__ __launch_bounds__(256) void elr2_kernel(const _Float16* __restrict__ h1,
                                                   const float* __restrict__ val,
                                                   const float* __restrict__ var_,
                                                   float* __restrict__ el,
                                                   float* __restrict__ er) {
    int gid = blockIdx.x * 256 + threadIdx.x;
    int w = gid >> 6;
    int lane = threadIdx.x & 63;
    if (w >= NN * 4) return;
    int n = w >> 2, h = w & 3;
    const _Float16* hr = h1 + (size_t)n * 256;
    const float* vp = val + h * 256;
    const float* rp = var_ + h * 256;
    float se = 0.f, sr = 0.f;
    for (int k = lane; k < 256; k += 64) {
        float x = (float)hr[k];
        se += x * vp[k];
        sr += x * rp[k];
    }
#pragma unroll
    for (int off = 32; off > 0; off >>= 1) {
        se += __shfl_down(se, off);
        sr += __shfl_down(sr, off);
    }
    if (lane == 0) { el[w] = se; er[w] = sr; }
}

// ---------------- aggregation: 1-wave blocks, half4 loads ----------------
// Block = 64 lanes = one node. Lane l owns cols 4l..4l+3 (head h = l>>4).
// p-phase: chunk = 16 edges x 4 heads = 64 lanes; den via shfl_xor.

// z-gather (layers 0 & 1): elu epilogue, f16 out [N,256].
__global__ __launch_bounds__(64) void agg_z64_kernel(const _Float16* __restrict__ z,
                                                     const float* __restrict__ el,
                                                     const float* __restrict__ er,
                                                     const int* __restrict__ offs,
                                                     const int* __restrict__ psrc,
                                                     const float* __restrict__ bias,
                                                     _Float16* __restrict__ out) {
    int n = blockIdx.x;
    int l = threadIdx.x;
    __shared__ float p_lds[16][4];
    __shared__ int src_lds[16];
    __shared__ float den_lds[4];
    if (l < 4) den_lds[l] = 0.f;
    int e_local = l >> 2, hh = l & 3;
    int h = l >> 4;
    float er_n = er[n * 4 + hh];
    int beg = offs[n], end = offs[n + 1];
    float a0 = 0.f, a1 = 0.f, a2 = 0.f, a3 = 0.f;
    for (int base = beg; base < end; base += 16) {
        int cnt = min(16, end - base);
        __syncthreads();
        float p = 0.f;
        if (e_local < cnt) {
            int s = psrc[base + e_local];
            if (hh == 0) src_lds[e_local] = s;
            float sc = el[s * 4 + hh] + er_n;
            sc = (sc > 0.f) ? sc : 0.2f * sc;
            p = __expf(sc);
            p_lds[e_local][hh] = p;
        }
        float d = p;
        d += __shfl_xor(d, 4);  d += __shfl_xor(d, 8);
        d += __shfl_xor(d, 16); d += __shfl_xor(d, 32);
        if (l < 4) den_lds[l] += d;
        __syncthreads();
        for (int e = 0; e < cnt; ++e) {
            half4 v = *(const half4*)(z + (size_t)src_lds[e] * 256 + (l << 2));
            float pe = p_lds[e][h];
            a0 += pe * (float)v[0];
            a1 += pe * (float)v[1];
            a2 += pe * (float)v[2];
            a3 += pe * (float)v[3];
        }
    }
    __syncthreads();
    float rd = 1.f / fmaxf(den_lds[h], 1e-9f);
    float vals[4] = {a0, a1, a2, a3};
    half4 o;
#pragma unroll
    for (int j = 0; j < 4; ++j) {
        float x = vals[j] * rd + bias[(l << 2) + j];
        x = (x > 0.f) ? x : (__expf(x) - 1.f);
        o[j] = (_Float16)x;
    }
    *(half4*)(out + (size_t)n * 256 + (l << 2)) = o;
}

// layer-2 aggregation of h1 (fp16) -> row-major f16 [N,1024] (final GEMM A).
__global__ __launch_bounds__(64) void aggH_64_kernel(const _Float16* __restrict__ h1,
                                                     const float* __restrict__ el,
                                                     const float* __restrict__ er,
                                                     const int* __restrict__ offs,
                                                     const int* __restrict__ psrc,
                                                     _Float16* __restrict__ oA) {
    int n = blockIdx.x;
    int l = threadIdx.x;
    __shared__ __align__(16) float p_lds[16][4];
    __shared__ int src_lds[16];
    __shared__ float den_lds[4];
    if (l < 4) den_lds[l] = 0.f;
    int e_local = l >> 2, hh = l & 3;
    float er_n = er[n * 4 + hh];
    int beg = offs[n], end = offs[n + 1];
    float acc[4][4] = {};   // [head][colj]
    for (int base = beg; base < end; base += 16) {
        int cnt = min(16, end - base);
        __syncthreads();
        float p = 0.f;
        if (e_local < cnt) {
            int s = psrc[base + e_local];
            if (hh == 0) src_lds[e_local] = s;
            float sc = el[s * 4 + hh] + er_n;
            sc = (sc > 0.f) ? sc : 0.2f * sc;
            p = __expf(sc);
            p_lds[e_local][hh] = p;
        }
        float d = p;
        d += __shfl_xor(d, 4);  d += __shfl_xor(d, 8);
        d += __shfl_xor(d, 16); d += __shfl_xor(d, 32);
        if (l < 4) den_lds[l] += d;
        __syncthreads();
        for (int e = 0; e < cnt; ++e) {
            half4 v = *(const half4*)(h1 + (size_t)src_lds[e] * 256 + (l << 2));
            float vf0 = (float)v[0], vf1 = (float)v[1];
            float vf2 = (float)v[2], vf3 = (float)v[3];
            floatx4 pv = *(const floatx4*)&p_lds[e][0];
#pragma unroll
            for (int hd = 0; hd < 4; ++hd) {
                acc[hd][0] += pv[hd] * vf0;
                acc[hd][1] += pv[hd] * vf1;
                acc[hd][2] += pv[hd] * vf2;
                acc[hd][3] += pv[hd] * vf3;
            }
        }
    }
    __syncthreads();
    size_t base_o = (size_t)n * 1024 + (l << 2);
#pragma unroll
    for (int hd = 0; hd < 4; ++hd) {
        float rd = 1.f / fmaxf(den_lds[hd], 1e-9f);
        half4 o;
#pragma unroll
        for (int j = 0; j < 4; ++j) o[j] = (_Float16)(acc[hd][j] * rd);
        *(half4*)(oA + base_o + hd * 256) = o;
    }
}

// ---------------- launch ----------------

extern "C" void kernel_launch(void* const* d_in, const int* in_sizes, int n_in,
                              void* d_out, int out_size, void* d_ws, size_t ws_size,
                              hipStream_t stream) {
    const float* feat = (const float*)d_in[0];
    const float* W0 = (const float*)d_in[1];
    const float* al0 = (const float*)d_in[2];
    const float* ar0 = (const float*)d_in[3];
    const float* b0 = (const float*)d_in[4];
    const float* W1 = (const float*)d_in[5];
    const float* al1 = (const float*)d_in[6];
    const float* ar1 = (const float*)d_in[7];
    const float* b1 = (const float*)d_in[8];
    const float* W2 = (const float*)d_in[9];
    const float* al2 = (const float*)d_in[10];
    const float* ar2 = (const float*)d_in[11];
    const float* b2 = (const float*)d_in[12];
    const int* src = (const int*)d_in[13];
    const int* dst = (const int*)d_in[14];
    float* out = (float*)d_out;

    // ---- workspace layout (~262.5 MB), time-multiplexed big slots ----
    float* slotA = (float*)d_ws;
    _Float16* zh = (_Float16*)slotA;                      // [N,256] fp16 (z slot)
    short* feathi = (short*)(slotA + (size_t)NN * 256);   // 50000*128 shorts
    short* featlo = feathi + (size_t)NN * 128;
    _Float16* Af16 = (_Float16*)slotA;                    // [N,1024] f16 (layer 2)
    float* slotB = slotA + (size_t)NN * 1024;
    _Float16* h0f = (_Float16*)slotB;                     // [N,256] f16
    _Float16* h1h = (_Float16*)slotB;                     // [N,256] f16 (layer 2)
    float* el = slotB + (size_t)NN * 256;                 // 200000
    float* er = el + (size_t)NN * NH_HEADS;               // 200000
    int* deg = (int*)(er + (size_t)NN * NH_HEADS);        // 50000
    int* offs = deg + NN;                                 // 50001 (+1 pad)
    int* cursor = offs + NN + 2;                          // 50000
    int* bsums = cursor + NN;                             // 256
    int* boffs = bsums + 256;                             // 256
    int* psrc = boffs + 256;                              // 800000 (+2 pad)
    short* Bh = (short*)(psrc + NE + 2);                  // 262144 shorts / half8s
    short* Bl = Bh + 262144;                              // 262144 shorts
    float* val = (float*)(Bl + 262144);                   // 1024
    float* var_ = val + 1024;                             // 1024

    // ---- CSR build (by dst) ----
    hipMemsetAsync(deg, 0, NN * sizeof(int), stream);
    hist_kernel<<<(NE + 255) / 256, 256, 0, stream>>>(dst, deg, NE);
    int nb = (NN + 255) / 256;
    scan_block_kernel<<<nb, 256, 0, stream>>>(deg, offs, bsums, NN);
    scan_sums_kernel<<<1, 256, 0, stream>>>(bsums, boffs, nb);
    add_offs_kernel<<<nb, 256, 0, stream>>>(offs, boffs, cursor, NN, NE);
    scatter_kernel<<<(NE + 255) / 256, 256, 0, stream>>>(src, dst, cursor, psrc, NE);

    int mb64 = (NN + 63) / 64; // 782

    // ---- layer 0: 128 -> 4x64, elu (bf16-pair GEMM, elr fused; z fp16) ----
    splitA_rm<<<(NN * 128 / 8 + 255) / 256, 256, 0, stream>>>(feat, feathi, featlo, NN * 128 / 8);
    splitB_kernel<<<(4096 + 255) / 256, 256, 0, stream>>>(W0, Bh, Bl, 128, 256);
    gemm_n256l<<<mb64, 256, 0, stream>>>(feathi, featlo, Bh, Bl, zh,
                                         al0, ar0, el, er, NN, 128);
    agg_z64_kernel<<<NN, 64, 0, stream>>>(zh, el, er, offs, psrc, b0, h0f);

    // ---- layer 1: 256 -> 4x64, elu (f16 GEMM: A=h0 single f16, B pair) ----
    splitB_f16_kernel<<<(8192 + 255) / 256, 256, 0, stream>>>(W1, (_Float16*)Bh,
                                                              (_Float16*)Bl, 256, 256);
    gemm_f16_n256<<<mb64, 256, 0, stream>>>(h0f, (const _Float16*)Bh, (const _Float16*)Bl,
                                            zh, al1, ar1, el, er, NN, 256);
    agg_z64_kernel<<<NN, 64, 0, stream>>>(zh, el, er, offs, psrc, b1, h1h);

    // ---- layer 2: score from aggregated h1, then f16 K=1024 projection ----
    proj_av_kernel<<<256, 256, 0, stream>>>(W2, al2, ar2, val, var_);
    elr2_kernel<<<NN, 256, 0, stream>>>(h1h, val, var_, el, er);
    aggH_64_kernel<<<NN, 64, 0, stream>>>(h1h, el, er, offs, psrc, Af16);
    splitB2_f16s_kernel<<<(32768 + 255) / 256, 256, 0, stream>>>(W2, (_Float16*)Bh);
    dim3 gfin(mb64, 2);
    gemm_f16_ns2<<<gfin, 256, 0, stream>>>(Af16, (const _Float16*)Bh, b2, out, NN, 1024);
}